// Round 1
// baseline (842.187 us; speedup 1.0000x reference)
//
#include <hip/hip_runtime.h>
#include <hip/hip_bf16.h>
#include <math.h>

// Problem constants
#define NN   4
#define MM   2048
#define CC   512
#define HH   8
#define DD   64
#define TK   16
#define NMR  8192      // NN*MM
#define QKVC 1536      // 3*CC

// f32(512**-0.5): NEP50 casts the python-float scale to f32 before the ufunc mul
#define SCALE32 ((float)0.044194173824159216)

typedef unsigned long long u64;
typedef unsigned int u32;

// strict f32 multiply that cannot be contracted into a downstream FMA
__device__ __forceinline__ float fmul_nf(float a, float b) {
  float p = a * b;
  asm("" : "+v"(p));
  return p;
}

// order-preserving f32 -> u32 (monotone for all finite floats)
__device__ __forceinline__ u32 ordf(float f) {
  u32 u = __float_as_uint(f);
  return u ^ (u32)(((int)u >> 31) | 0x80000000);
}
__device__ __forceinline__ float unordf(u32 k) {
  u32 u = (k & 0x80000000u) ? (k ^ 0x80000000u) : ~k;
  return __uint_as_float(u);
}
// packed sort key: hi = ordered value, lo = ~idx  =>  u64 '>' == (v desc, idx asc)
__device__ __forceinline__ u64 packkey(float v, u32 notidx) {
  return ((u64)ordf(v) << 32) | (u64)notidx;
}

// descending compare-swap / select-max on packed keys
#define CSW(a,b) { u64 _x=(a), _y=(b); bool _g = _x < _y; (a) = _g ? _y : _x; (b) = _g ? _x : _y; }
#define CMX(a,b) { if ((a) < (b)) (a) = (b); }

// optimal 19-CS sorting network, 8 elements, descending
#define SORT8(N) \
  CSW(N[0],N[1]); CSW(N[2],N[3]); CSW(N[4],N[5]); CSW(N[6],N[7]); \
  CSW(N[0],N[2]); CSW(N[1],N[3]); CSW(N[4],N[6]); CSW(N[5],N[7]); \
  CSW(N[1],N[2]); CSW(N[5],N[6]); CSW(N[0],N[4]); CSW(N[3],N[7]); \
  CSW(N[1],N[5]); CSW(N[2],N[6]); \
  CSW(N[1],N[4]); CSW(N[3],N[6]); \
  CSW(N[2],N[4]); CSW(N[3],N[5]); \
  CSW(N[3],N[4]);

// bitonic cleanup of a 16-long bitonic sequence -> descending sorted
#define BITONIC16(R) \
  CSW(R[0],R[8]); CSW(R[1],R[9]); CSW(R[2],R[10]); CSW(R[3],R[11]); \
  CSW(R[4],R[12]); CSW(R[5],R[13]); CSW(R[6],R[14]); CSW(R[7],R[15]); \
  CSW(R[0],R[4]); CSW(R[1],R[5]); CSW(R[2],R[6]); CSW(R[3],R[7]); \
  CSW(R[8],R[12]); CSW(R[9],R[13]); CSW(R[10],R[14]); CSW(R[11],R[15]); \
  CSW(R[0],R[2]); CSW(R[1],R[3]); CSW(R[4],R[6]); CSW(R[5],R[7]); \
  CSW(R[8],R[10]); CSW(R[9],R[11]); CSW(R[12],R[14]); CSW(R[13],R[15]); \
  CSW(R[0],R[1]); CSW(R[2],R[3]); CSW(R[4],R[5]); CSW(R[6],R[7]); \
  CSW(R[8],R[9]); CSW(R[10],R[11]); CSW(R[12],R[13]); CSW(R[14],R[15]);

// merge sorted-8 N (desc) into running sorted-16 R (desc), keep top-16 of union
#define MERGE8INTO16(R,N) \
  CMX(R[8],N[7]); CMX(R[9],N[6]); CMX(R[10],N[5]); CMX(R[11],N[4]); \
  CMX(R[12],N[3]); CMX(R[13],N[2]); CMX(R[14],N[1]); CMX(R[15],N[0]); \
  BITONIC16(R);

// ---------------- Kernel 0: conv + residual -> x2 (memory-bound pre-pass) ------------
// x2 = x + (((x[-1]*w0 + x[0]*w1) + x[1]*w2) + cb)   [ufunc order, no FMA]
// Bit-identical chain to the previous fused version; computed ONCE instead of per
// column-block (12x) inside the QKV GEMM.
__global__ __launch_bounds__(256) void conv_x2_kernel(
    const float* __restrict__ x,
    const float* __restrict__ cw,
    const float* __restrict__ cb,
    float* __restrict__ X2)
{
  int t  = blockIdx.x * 256 + threadIdx.x;   // one thread per 4 channels
  int r  = t >> 7;                           // 128 threads per row
  int c4 = (t & 127) << 2;
  int m  = r & (MM - 1);                     // position within sequence

  const float* xp = x + (size_t)r * CC + c4;
  float4 x0  = *(const float4*)xp;
  float4 xm1 = make_float4(0.f, 0.f, 0.f, 0.f);
  float4 xp1 = make_float4(0.f, 0.f, 0.f, 0.f);
  if (m > 0)      xm1 = *(const float4*)(xp - CC);
  if (m < MM - 1) xp1 = *(const float4*)(xp + CC);

  // conv weights: layout cw[c*3 + k]; 4 channels => 12 consecutive floats (16B-aligned)
  float4 wa = *(const float4*)(cw + c4 * 3);
  float4 wb = *(const float4*)(cw + c4 * 3 + 4);
  float4 wc = *(const float4*)(cw + c4 * 3 + 8);
  float4 cbv = *(const float4*)(cb + c4);
  const float w[12] = {wa.x, wa.y, wa.z, wa.w, wb.x, wb.y, wb.z, wb.w,
                       wc.x, wc.y, wc.z, wc.w};
  const float xe[4]  = {x0.x,  x0.y,  x0.z,  x0.w};
  const float xme[4] = {xm1.x, xm1.y, xm1.z, xm1.w};
  const float xpe[4] = {xp1.x, xp1.y, xp1.z, xp1.w};
  const float cbe[4] = {cbv.x, cbv.y, cbv.z, cbv.w};

  float o[4];
  #pragma unroll
  for (int e = 0; e < 4; ++e) {
    float p0 = fmul_nf(xme[e], w[e*3 + 0]);
    float p1 = fmul_nf(xe[e],  w[e*3 + 1]);
    float p2 = fmul_nf(xpe[e], w[e*3 + 2]);
    float s = p0 + p1;
    s = s + p2;
    s = s + cbe[e];
    o[e] = xe[e] + s;                        // x2 = x + pos
  }
  *(float4*)&X2[(size_t)r * CC + c4] = make_float4(o[0], o[1], o[2], o[3]);
}

// ---------------- Kernel 1: QKV GEMM, 128x128 tile, 8x8 microtile --------------------
// q/k/v = x2 @ w_qkv (+bias): f32, sequential k=0..511, FMA per step (chain order
// identical to r9 64x64 version -> bit-identical outputs).
// LDS demand per FMA halves vs 64x64/4x4: per kk, 4 ds_read_b128 feed 64 FMAs.
// Microtile cols/rows split {g*4, 64+g*4} so each b128 read-wave covers 256
// contiguous bytes -> worst 2-way bank aliasing (free).
__global__ __launch_bounds__(256) void gemm_qkv128_kernel(
    const float* __restrict__ X2,
    const float* __restrict__ W,
    const float* __restrict__ bqkv,
    float* __restrict__ Q, float* __restrict__ K, float* __restrict__ V)
{
  __shared__ float As[16][128];   // [k][row] transposed tile of x2
  __shared__ float Bs[16][128];   // [k][col] weights

  int tid = threadIdx.x;
  int bm = blockIdx.x, bn = blockIdx.y;
  int tx = tid & 15, ty = tid >> 4;

  // A staging: thread loads 8 k-values of one row, writes transposed
  int sr  = tid >> 1;             // row 0..127
  int sk8 = (tid & 1) << 3;       // k offset 0 or 8
  const float* ap = X2 + (size_t)(bm * 128 + sr) * CC + sk8;

  // B staging: thread loads 8 consecutive cols of one weight row
  int wr = tid >> 4;              // 0..15
  int wc = (tid & 15) << 3;       // 0..120
  const float* wp = W + (size_t)wr * QKVC + bn * 128 + wc;

  float acc[8][8];
  #pragma unroll
  for (int i = 0; i < 8; ++i)
    #pragma unroll
    for (int j = 0; j < 8; ++j) acc[i][j] = 0.f;

  for (int kt = 0; kt < CC/16; ++kt) {
    float4 a0 = *(const float4*)(ap + kt*16);
    float4 a1 = *(const float4*)(ap + kt*16 + 4);
    float4 w0 = *(const float4*)(wp + (size_t)kt*16*QKVC);
    float4 w1 = *(const float4*)(wp + (size_t)kt*16*QKVC + 4);

    __syncthreads();
    As[sk8+0][sr] = a0.x; As[sk8+1][sr] = a0.y;
    As[sk8+2][sr] = a0.z; As[sk8+3][sr] = a0.w;
    As[sk8+4][sr] = a1.x; As[sk8+5][sr] = a1.y;
    As[sk8+6][sr] = a1.z; As[sk8+7][sr] = a1.w;
    *(float4*)&Bs[wr][wc]     = w0;
    *(float4*)&Bs[wr][wc + 4] = w1;
    __syncthreads();

    #pragma unroll
    for (int kk = 0; kk < 16; ++kk) {
      float4 aA = *(const float4*)&As[kk][(ty<<2)];
      float4 aB = *(const float4*)&As[kk][64 + (ty<<2)];
      float4 bA = *(const float4*)&Bs[kk][(tx<<2)];
      float4 bB = *(const float4*)&Bs[kk][64 + (tx<<2)];
      const float ae[8] = {aA.x, aA.y, aA.z, aA.w, aB.x, aB.y, aB.z, aB.w};
      const float be[8] = {bA.x, bA.y, bA.z, bA.w, bB.x, bB.y, bB.z, bB.w};
      #pragma unroll
      for (int i = 0; i < 8; ++i)
        #pragma unroll
        for (int j = 0; j < 8; ++j)
          acc[i][j] = __builtin_fmaf(ae[i], be[j], acc[i][j]);
    }
  }

  int seg = bn >> 2;                        // 0=q, 1=k, 2=v  (4 col-blocks per seg)
  float* dst = (seg == 0) ? Q : ((seg == 1) ? K : V);
  int colA = (bn & 3) * 128 + (tx << 2);
  int colB = colA + 64;

  float bb[8];
  #pragma unroll
  for (int j = 0; j < 4; ++j) {
    bb[j]     = bqkv[bn * 128 + (tx << 2) + j];
    bb[4 + j] = bqkv[bn * 128 + 64 + (tx << 2) + j];
  }
  #pragma unroll
  for (int i = 0; i < 8; ++i) {
    int row = bm * 128 + (ty << 2) + (i & 3) + ((i >> 2) << 6);
    float4 o0 = make_float4(acc[i][0] + bb[0], acc[i][1] + bb[1],
                            acc[i][2] + bb[2], acc[i][3] + bb[3]);
    float4 o1 = make_float4(acc[i][4] + bb[4], acc[i][5] + bb[5],
                            acc[i][6] + bb[6], acc[i][7] + bb[7]);
    *(float4*)&dst[(size_t)row * CC + colA] = o0;
    *(float4*)&dst[(size_t)row * CC + colB] = o1;
  }
}

// ---------------- Kernel 2: f32 logits + top-16 + softmax + V-gather -----------------
// UNCHANGED from the 880us version (exact top-k semantics; next round's counters
// decide whether it is LDS- or VALU-bound before restructuring).
__global__ __launch_bounds__(256) void route_attn_kernel(
    const float* __restrict__ Q,
    const float* __restrict__ K,
    const float* __restrict__ V,
    float* __restrict__ attn)
{
  __shared__ float qs[32][68];    // q*scale32 (f32-rounded)
  __shared__ float ks[128][68];   // staged k-tile
  int bq = blockIdx.x;
  int n = bq >> 9, h = (bq >> 6) & 7, qt = bq & 63;
  int tid = threadIdx.x;
  int s = tid & 15, qi = tid >> 4;   // thread owns queries qi and qi+16
  size_t nbase = (size_t)n * MM * CC;

  // stage q tile (32 rows x 16 float4), scale applied once in f32
  #pragma unroll
  for (int rep = 0; rep < 2; ++rep) {
    int idx = tid + (rep<<8);
    int r = idx >> 4, c4 = idx & 15;
    const float* p = Q + nbase + (size_t)(qt*32 + r)*CC + h*DD + (c4<<2);
    float4 v = *(const float4*)p;
    qs[r][(c4<<2)+0] = v.x * SCALE32;
    qs[r][(c4<<2)+1] = v.y * SCALE32;
    qs[r][(c4<<2)+2] = v.z * SCALE32;
    qs[r][(c4<<2)+3] = v.w * SCALE32;
  }

  u64 runA[16], runB[16];
  #pragma unroll
  for (int i=0;i<16;i++){ runA[i]=0ull; runB[i]=0ull; }  // key 0 < any real logit key

  for (int kt = 0; kt < 16; ++kt) {      // 16 tiles x 128 keys
    __syncthreads();
    #pragma unroll
    for (int rep = 0; rep < 8; ++rep) {
      int idx = tid + (rep<<8);          // 0..2047
      int r = idx >> 4, c4 = idx & 15;
      *(float4*)&ks[r][c4<<2] =
          *(const float4*)(K + nbase + (size_t)(kt*128 + r)*CC + h*DD + (c4<<2));
    }
    __syncthreads();

    float accA[8], accB[8];
    #pragma unroll
    for (int j=0;j<8;j++){ accA[j]=0.f; accB[j]=0.f; }

    for (int t4 = 0; t4 < 16; ++t4) {    // rolled: keeps VGPR pressure low
      float4 qa = *(const float4*)&qs[qi][t4<<2];
      float4 qb = *(const float4*)&qs[qi+16][t4<<2];
      #pragma unroll
      for (int j = 0; j < 8; ++j) {
        float4 kv = *(const float4*)&ks[s + (j<<4)][t4<<2];
        // separate mul+add, sequential in t — bit-identical np-einsum chain
        accA[j] = accA[j] + fmul_nf(qa.x, kv.x);
        accA[j] = accA[j] + fmul_nf(qa.y, kv.y);
        accA[j] = accA[j] + fmul_nf(qa.z, kv.z);
        accA[j] = accA[j] + fmul_nf(qa.w, kv.w);
        accB[j] = accB[j] + fmul_nf(qb.x, kv.x);
        accB[j] = accB[j] + fmul_nf(qb.y, kv.y);
        accB[j] = accB[j] + fmul_nf(qb.z, kv.z);
        accB[j] = accB[j] + fmul_nf(qb.w, kv.w);
      }
    }

    // batched selection: pack, sort-8, bitonic-merge into running top-16
    u64 NA[8], NB[8];
    #pragma unroll
    for (int j=0;j<8;j++) {
      u32 ni = ~(u32)(kt*128 + s + (j<<4));
      NA[j] = packkey(accA[j], ni);
      NB[j] = packkey(accB[j], ni);
    }
    SORT8(NA); SORT8(NB);
    MERGE8INTO16(runA, NA);
    MERGE8INTO16(runB, NB);
  }

  // 16-lane butterfly merge + epilogue, list A then list B
  #pragma unroll
  for (int which = 0; which < 2; ++which) {
    u64 lv[16];
    #pragma unroll
    for (int i=0;i<16;i++) lv[i] = which ? runB[i] : runA[i];

    #pragma unroll
    for (int off = 1; off < 16; off <<= 1) {
      u64 nv[16];
      #pragma unroll
      for (int i = 0; i < 16; ++i) {       // half-cleaner: union top-16 multiset
        u64 bv = __shfl_xor(lv[15 - i], off);
        nv[i] = (lv[i] < bv) ? bv : lv[i];
      }
      BITONIC16(nv);                       // bitonic -> sorted desc
      #pragma unroll
      for (int i = 0; i < 16; ++i) lv[i] = nv[i];
    }

    // unpack + softmax (f32, sequential — same as passing r9 chain) + V gather
    float vv0 = unordf((u32)(lv[0] >> 32));   // sorted desc -> max
    float e[16]; float Z = 0.f;
    int ki[16];
    #pragma unroll
    for (int i=0;i<16;i++){
      float vi = unordf((u32)(lv[i] >> 32));
      e[i] = expf(vi - vv0); Z += e[i];
      ki[i] = (int)(~(u32)lv[i]) & (MM - 1);  // masked: can never read wild
    }
    float invZ = 1.f / Z;
    float4 o = make_float4(0.f,0.f,0.f,0.f);
    #pragma unroll
    for (int i=0;i<16;i++) {
      const float* vp = V + nbase + (size_t)ki[i]*CC + h*DD + (s<<2);
      float4 vvv = *(const float4*)vp;
      float w = e[i]*invZ;
      o.x += w*vvv.x; o.y += w*vvv.y; o.z += w*vvv.z; o.w += w*vvv.w;
    }
    int qrow = qt*32 + qi + (which ? 16 : 0);
    *(float4*)&attn[nbase + (size_t)qrow*CC + h*DD + (s<<2)] = o;
  }
}

// ---------------- Kernel 3: out = attn @ w_o + b_o, 128x128 tile ---------------------
__global__ __launch_bounds__(256) void gemm_out128_kernel(
    const float* __restrict__ A,
    const float* __restrict__ W,
    const float* __restrict__ bias,
    float* __restrict__ O)
{
  __shared__ float As[16][128];
  __shared__ float Bs[16][128];

  int tid = threadIdx.x;
  int bm = blockIdx.x, bn = blockIdx.y;
  int tx = tid & 15, ty = tid >> 4;

  int sr  = tid >> 1;
  int sk8 = (tid & 1) << 3;
  const float* ap = A + (size_t)(bm * 128 + sr) * CC + sk8;

  int wr = tid >> 4;
  int wc = (tid & 15) << 3;
  const float* wp = W + (size_t)wr * CC + bn * 128 + wc;

  float acc[8][8];
  #pragma unroll
  for (int i = 0; i < 8; ++i)
    #pragma unroll
    for (int j = 0; j < 8; ++j) acc[i][j] = 0.f;

  for (int kt = 0; kt < CC/16; ++kt) {
    float4 a0 = *(const float4*)(ap + kt*16);
    float4 a1 = *(const float4*)(ap + kt*16 + 4);
    float4 w0 = *(const float4*)(wp + (size_t)kt*16*CC);
    float4 w1 = *(const float4*)(wp + (size_t)kt*16*CC + 4);

    __syncthreads();
    As[sk8+0][sr] = a0.x; As[sk8+1][sr] = a0.y;
    As[sk8+2][sr] = a0.z; As[sk8+3][sr] = a0.w;
    As[sk8+4][sr] = a1.x; As[sk8+5][sr] = a1.y;
    As[sk8+6][sr] = a1.z; As[sk8+7][sr] = a1.w;
    *(float4*)&Bs[wr][wc]     = w0;
    *(float4*)&Bs[wr][wc + 4] = w1;
    __syncthreads();

    #pragma unroll
    for (int kk = 0; kk < 16; ++kk) {
      float4 aA = *(const float4*)&As[kk][(ty<<2)];
      float4 aB = *(const float4*)&As[kk][64 + (ty<<2)];
      float4 bA = *(const float4*)&Bs[kk][(tx<<2)];
      float4 bB = *(const float4*)&Bs[kk][64 + (tx<<2)];
      const float ae[8] = {aA.x, aA.y, aA.z, aA.w, aB.x, aB.y, aB.z, aB.w};
      const float be[8] = {bA.x, bA.y, bA.z, bA.w, bB.x, bB.y, bB.z, bB.w};
      #pragma unroll
      for (int i = 0; i < 8; ++i)
        #pragma unroll
        for (int j = 0; j < 8; ++j)
          acc[i][j] = __builtin_fmaf(ae[i], be[j], acc[i][j]);
    }
  }

  int colA = bn * 128 + (tx << 2);
  int colB = colA + 64;
  float bb[8];
  #pragma unroll
  for (int j = 0; j < 4; ++j) {
    bb[j]     = bias[colA + j];
    bb[4 + j] = bias[colB + j];
  }
  #pragma unroll
  for (int i = 0; i < 8; ++i) {
    int row = bm * 128 + (ty << 2) + (i & 3) + ((i >> 2) << 6);
    float4 o0 = make_float4(acc[i][0] + bb[0], acc[i][1] + bb[1],
                            acc[i][2] + bb[2], acc[i][3] + bb[3]);
    float4 o1 = make_float4(acc[i][4] + bb[4], acc[i][5] + bb[5],
                            acc[i][6] + bb[6], acc[i][7] + bb[7]);
    *(float4*)&O[(size_t)row * CC + colA] = o0;
    *(float4*)&O[(size_t)row * CC + colB] = o1;
  }
}

// ---------------- launch --------------------------------------------------------------
extern "C" void kernel_launch(void* const* d_in, const int* in_sizes, int n_in,
                              void* d_out, int out_size, void* d_ws, size_t ws_size,
                              hipStream_t stream) {
  (void)in_sizes; (void)n_in; (void)out_size;
  const float* x      = (const float*)d_in[0];
  const float* conv_w = (const float*)d_in[1];
  const float* conv_b = (const float*)d_in[2];
  const float* w_qkv  = (const float*)d_in[3];
  const float* b_qkv  = (const float*)d_in[4];
  const float* w_o    = (const float*)d_in[5];
  const float* b_o    = (const float*)d_in[6];
  float* out = (float*)d_out;

  size_t perbuf_b = (size_t)NMR * CC;               // batched buffer elems
  bool batched = ws_size >= 4 * perbuf_b * sizeof(float);   // 64 MB

  if (batched) {
    float* Qb = (float*)d_ws;
    float* Kb = Qb + perbuf_b;
    float* Vb = Kb + perbuf_b;
    float* at = Vb + perbuf_b;
    // x2 lives in 'at' (dead before route_attn overwrites it with attn output)
    conv_x2_kernel<<<NMR/2, 256, 0, stream>>>(x, conv_w, conv_b, at);
    gemm_qkv128_kernel<<<dim3(NMR/128, QKVC/128), 256, 0, stream>>>(
        at, w_qkv, b_qkv, Qb, Kb, Vb);
    route_attn_kernel<<<NN*HH*(MM/32), 256, 0, stream>>>(Qb, Kb, Vb, at);
    gemm_out128_kernel<<<dim3(NMR/128, CC/128), 256, 0, stream>>>(at, w_o, b_o, out);
  } else {
    size_t perbuf = (size_t)MM * CC;                // per-n fallback (16 MB)
    float* Qb = (float*)d_ws;
    float* Kb = Qb + perbuf;
    float* Vb = Kb + perbuf;
    float* at = Vb + perbuf;
    for (int n = 0; n < NN; ++n) {
      const float* xn = x + (size_t)n*MM*CC;
      conv_x2_kernel<<<MM/2, 256, 0, stream>>>(xn, conv_w, conv_b, at);
      gemm_qkv128_kernel<<<dim3(MM/128, QKVC/128), 256, 0, stream>>>(
          at, w_qkv, b_qkv, Qb, Kb, Vb);
      route_attn_kernel<<<HH*(MM/32), 256, 0, stream>>>(Qb, Kb, Vb, at);
      gemm_out128_kernel<<<dim3(MM/128, CC/128), 256, 0, stream>>>(
          at, w_o, b_o, out + (size_t)n*MM*CC);
    }
  }
}